// Round 8
// baseline (51.722 us; speedup 1.0000x reference)
//
#include <hip/hip_runtime.h>
#include <math.h>
#include <stdint.h>

#define NHEAD 4
#define DD 100
#define NW 39            // word rows
#define BLOCK 64         // ONE wave per block = one site, zero barriers

typedef __attribute__((address_space(3))) uint32_t lds_t;
typedef const __attribute__((address_space(1))) uint32_t glb_t;

__global__ __launch_bounds__(BLOCK) void ts_enc(
    const float* __restrict__ x,       // [4800][40][100]
    const float* __restrict__ w_att,   // [4][100]
    const float* __restrict__ b_att,   // [4][100]
    float* __restrict__ out)           // [4800][400]
{
    __shared__ float tile[40 * DD];    // 16 KB, private to this wave

    const int lane = threadIdx.x;      // 0..63
    const float* xsite = x + (size_t)blockIdx.x * (40 * DD);

    // ---- stage tile: per-wave async DMA; wait on OWN vmcnt only (no barrier) ----
    #pragma unroll
    for (int i = 0; i < 16; ++i) {
        const int cf = i * 64 + lane;               // float4 chunk 0..1023
        if (cf < 1000) {
            glb_t* g = (glb_t*)(xsite + cf * 4);
            lds_t* l = (lds_t*)(tile + i * 256);    // wave-uniform base; lane*16B auto
            __builtin_amdgcn_global_load_lds(g, l, 16, 0, 0);
        }
    }
    asm volatile("s_waitcnt vmcnt(0)" ::: "memory");
    __builtin_amdgcn_sched_barrier(0);

    // ---- Phase A: lane = n; all 25 d-chunks, all 4 heads; acc in registers ----
    // te*leaky(p) == (0.65*te)*p + (0.35*te)*|p|  (|p| = free modifier)
    const bool act  = lane < NW;
    const int  nrow = act ? lane : NW - 1;          // clamp idle lanes (dup of n=38)
    const float* wrow = tile + (1 + nrow) * DD;

    float acc0 = 0.f, acc1 = 0.f, acc2 = 0.f, acc3 = 0.f;

#define HEAD_BODY(h, acch) { \
        const float4 w4 = *(const float4*)(w_att + (h) * DD + c * 4); \
        const float4 b4 = *(const float4*)(b_att + (h) * DD + c * 4); \
        float p0 = fmaf(v4.x, w4.x, b4.x); \
        float p1 = fmaf(v4.y, w4.y, b4.y); \
        float p2 = fmaf(v4.z, w4.z, b4.z); \
        float p3 = fmaf(v4.w, w4.w, b4.w); \
        float t  = fmaf(a65x, p0, fmaf(a35x, fabsf(p0), acch)); \
        t        = fmaf(a65y, p1, fmaf(a35y, fabsf(p1), t)); \
        t        = fmaf(a65z, p2, fmaf(a35z, fabsf(p2), t)); \
        acch     = fmaf(a65w, p3, fmaf(a35w, fabsf(p3), t)); }

    #pragma unroll
    for (int c = 0; c < 25; ++c) {
        const float4 te4 = *(const float4*)(tile + c * 4);   // broadcast ds_read
        const float4 v4  = *(const float4*)(wrow + c * 4);   // per-lane row read
        const float a65x = 0.65f * te4.x, a35x = 0.35f * te4.x;
        const float a65y = 0.65f * te4.y, a35y = 0.35f * te4.y;
        const float a65z = 0.65f * te4.z, a35z = 0.35f * te4.z;
        const float a65w = 0.65f * te4.w, a35w = 0.35f * te4.w;
        HEAD_BODY(0, acc0)
        HEAD_BODY(1, acc1)
        HEAD_BODY(2, acc2)
        HEAD_BODY(3, acc3)
    }
#undef HEAD_BODY

    // ---- Phase B: 4 in-wave softmaxes (lane = n); all in registers ----
    float m0 = acc0, m1 = acc1, m2 = acc2, m3 = acc3;
    #pragma unroll
    for (int off = 32; off; off >>= 1) {
        m0 = fmaxf(m0, __shfl_xor(m0, off));
        m1 = fmaxf(m1, __shfl_xor(m1, off));
        m2 = fmaxf(m2, __shfl_xor(m2, off));
        m3 = fmaxf(m3, __shfl_xor(m3, off));
    }
    float p0 = act ? __expf(acc0 - m0) : 0.f;   // idle lanes contribute 0 to sums
    float p1 = act ? __expf(acc1 - m1) : 0.f;
    float p2 = act ? __expf(acc2 - m2) : 0.f;
    float p3 = act ? __expf(acc3 - m3) : 0.f;
    float s0 = p0, s1 = p1, s2 = p2, s3 = p3;
    #pragma unroll
    for (int off = 32; off; off >>= 1) {
        s0 += __shfl_xor(s0, off);
        s1 += __shfl_xor(s1, off);
        s2 += __shfl_xor(s2, off);
        s3 += __shfl_xor(s3, off);
    }
    const float a0 = p0 / s0;   // lane n holds att[h][n]
    const float a1 = p1 / s1;
    const float a2 = p2 / s2;
    const float a3 = p3 / s3;

    // ---- Phase C: lane = float2 d-chunk (50 active); att via v_readlane (VALU);
    //      one ds_read_b64 per n with immediate offset; all 4 heads per lane ----
    const int l2 = lane < 50 ? lane : 49;
    const float* wbase = tile + DD + l2 * 2;
    float2 o0 = {0.f, 0.f}, o1 = {0.f, 0.f}, o2 = {0.f, 0.f}, o3 = {0.f, 0.f};
    #pragma unroll
    for (int n = 0; n < NW; ++n) {
        const float2 wd = *(const float2*)(wbase + n * DD);
        const float t0 = __builtin_bit_cast(float, __builtin_amdgcn_readlane(__builtin_bit_cast(int, a0), n));
        const float t1 = __builtin_bit_cast(float, __builtin_amdgcn_readlane(__builtin_bit_cast(int, a1), n));
        const float t2 = __builtin_bit_cast(float, __builtin_amdgcn_readlane(__builtin_bit_cast(int, a2), n));
        const float t3 = __builtin_bit_cast(float, __builtin_amdgcn_readlane(__builtin_bit_cast(int, a3), n));
        o0.x = fmaf(t0, wd.x, o0.x); o0.y = fmaf(t0, wd.y, o0.y);
        o1.x = fmaf(t1, wd.x, o1.x); o1.y = fmaf(t1, wd.y, o1.y);
        o2.x = fmaf(t2, wd.x, o2.x); o2.y = fmaf(t2, wd.y, o2.y);
        o3.x = fmaf(t3, wd.x, o3.x); o3.y = fmaf(t3, wd.y, o3.y);
    }
    if (lane < 50) {
        float* ob = out + (size_t)blockIdx.x * (NHEAD * DD) + lane * 2;
        *(float2*)(ob)          = o0;
        *(float2*)(ob + DD)     = o1;
        *(float2*)(ob + 2 * DD) = o2;
        *(float2*)(ob + 3 * DD) = o3;
    }
}

extern "C" void kernel_launch(void* const* d_in, const int* in_sizes, int n_in,
                              void* d_out, int out_size, void* d_ws, size_t ws_size,
                              hipStream_t stream) {
    const float* x     = (const float*)d_in[0];
    const float* w_att = (const float*)d_in[1];
    const float* b_att = (const float*)d_in[2];
    float* out = (float*)d_out;

    const int sites = 8 * 30 * 20;   // 4800
    ts_enc<<<sites, BLOCK, 0, stream>>>(x, w_att, b_att, out);
}

// Round 9
// 43.338 us; speedup vs baseline: 1.1935x; 1.1935x over previous
//
#include <hip/hip_runtime.h>
#include <math.h>
#include <stdint.h>

#define NHEAD 4
#define DD 100
#define NW 39            // word rows
#define BLOCK 64         // one wave per site; no barriers, no tile staging

typedef float v2f __attribute__((ext_vector_type(2)));

__global__ __launch_bounds__(BLOCK, 4) void ts_enc(
    const float* __restrict__ x,       // [4800][40][100]
    const float* __restrict__ w_att,   // [4][100]
    const float* __restrict__ b_att,   // [4][100]
    float* __restrict__ out)           // [4800][400]
{
    __shared__ float att_s[40 * NHEAD];   // 640 B — the ONLY LDS

    const int lane = threadIdx.x;
    const float* xsite = x + (size_t)blockIdx.x * (40 * DD);

    // ---- Phase A: lane = n; rows straight from global (L1/L2); packed f32 math ----
    // leaky(p) = max(p, 0.3f*p)  (exact for all p)
    const bool act  = lane < NW;
    const int  nrow = act ? lane : NW - 1;          // clamped lanes dup row 38
    const float* wrow = xsite + (1 + nrow) * DD;

    v2f acc0a = {0,0}, acc0b = {0,0}, acc1a = {0,0}, acc1b = {0,0};
    v2f acc2a = {0,0}, acc2b = {0,0}, acc3a = {0,0}, acc3b = {0,0};

#define HEADP(h, accA, accB) { \
        v2f w01 = *(const v2f*)(w_att + (h) * DD + c * 4); \
        v2f w23 = *(const v2f*)(w_att + (h) * DD + c * 4 + 2); \
        asm("" : "+v"(w01), "+v"(w23)); \
        const v2f b01 = *(const v2f*)(b_att + (h) * DD + c * 4); \
        const v2f b23 = *(const v2f*)(b_att + (h) * DD + c * 4 + 2); \
        const v2f p01 = x01 * w01 + b01; \
        const v2f p23 = x23 * w23 + b23; \
        const v2f l01 = __builtin_elementwise_max(p01, 0.3f * p01); \
        const v2f l23 = __builtin_elementwise_max(p23, 0.3f * p23); \
        accA = t01 * l01 + accA; \
        accB = t23 * l23 + accB; }

    #pragma unroll
    for (int c = 0; c < 25; ++c) {
        const v2f x01 = *(const v2f*)(wrow + c * 4);
        const v2f x23 = *(const v2f*)(wrow + c * 4 + 2);
        const v2f t01 = *(const v2f*)(xsite + c * 4);    // type_emb (uniform)
        const v2f t23 = *(const v2f*)(xsite + c * 4 + 2);
        HEADP(0, acc0a, acc0b)
        HEADP(1, acc1a, acc1b)
        HEADP(2, acc2a, acc2b)
        HEADP(3, acc3a, acc3b)
    }
#undef HEADP

    float sc0 = (acc0a.x + acc0a.y) + (acc0b.x + acc0b.y);
    float sc1 = (acc1a.x + acc1a.y) + (acc1b.x + acc1b.y);
    float sc2 = (acc2a.x + acc2a.y) + (acc2b.x + acc2b.y);
    float sc3 = (acc3a.x + acc3a.y) + (acc3b.x + acc3b.y);

    // ---- Phase B: 4 in-register softmaxes over n ----
    float m0 = sc0, m1 = sc1, m2 = sc2, m3 = sc3;
    #pragma unroll
    for (int off = 32; off; off >>= 1) {
        m0 = fmaxf(m0, __shfl_xor(m0, off));
        m1 = fmaxf(m1, __shfl_xor(m1, off));
        m2 = fmaxf(m2, __shfl_xor(m2, off));
        m3 = fmaxf(m3, __shfl_xor(m3, off));
    }
    float p0 = act ? __expf(sc0 - m0) : 0.f;
    float p1 = act ? __expf(sc1 - m1) : 0.f;
    float p2 = act ? __expf(sc2 - m2) : 0.f;
    float p3 = act ? __expf(sc3 - m3) : 0.f;
    float s0 = p0, s1 = p1, s2 = p2, s3 = p3;
    #pragma unroll
    for (int off = 32; off; off >>= 1) {
        s0 += __shfl_xor(s0, off);
        s1 += __shfl_xor(s1, off);
        s2 += __shfl_xor(s2, off);
        s3 += __shfl_xor(s3, off);
    }
    if (act) {
        const float4 av = make_float4(p0 / s0, p1 / s1, p2 / s2, p3 / s3);
        *(float4*)&att_s[lane * 4] = av;     // ds_write_b128; same-wave, no barrier
    }

    // ---- Phase C: lane = float2 d-chunk (50 active); rows coalesced from global;
    //      att broadcast from 640B LDS (1 b128 per n serves all heads) ----
    const int l2 = lane < 50 ? lane : 49;
    const float* wbase = xsite + DD + l2 * 2;
    v2f o0 = {0,0}, o1 = {0,0}, o2 = {0,0}, o3 = {0,0};
    #pragma unroll
    for (int n = 0; n < NW; ++n) {
        const float4 at = *(const float4*)&att_s[n * 4];   // broadcast read
        const v2f wd = *(const v2f*)(wbase + n * DD);      // 400B coalesced row
        o0 += at.x * wd;
        o1 += at.y * wd;
        o2 += at.z * wd;
        o3 += at.w * wd;
    }
    if (lane < 50) {
        float* ob = out + (size_t)blockIdx.x * (NHEAD * DD) + lane * 2;
        *(v2f*)(ob)          = o0;
        *(v2f*)(ob + DD)     = o1;
        *(v2f*)(ob + 2 * DD) = o2;
        *(v2f*)(ob + 3 * DD) = o3;
    }
}

extern "C" void kernel_launch(void* const* d_in, const int* in_sizes, int n_in,
                              void* d_out, int out_size, void* d_ws, size_t ws_size,
                              hipStream_t stream) {
    const float* x     = (const float*)d_in[0];
    const float* w_att = (const float*)d_in[1];
    const float* b_att = (const float*)d_in[2];
    float* out = (float*)d_out;

    const int sites = 8 * 30 * 20;   // 4800
    ts_enc<<<sites, BLOCK, 0, stream>>>(x, w_att, b_att, out);
}